// Round 4
// baseline (199.269 us; speedup 1.0000x reference)
//
#include <hip/hip_runtime.h>

typedef __attribute__((ext_vector_type(4)))  float f32x4;
typedef __attribute__((ext_vector_type(16))) float f32x16;
typedef __attribute__((ext_vector_type(8)))  short short8;
typedef __attribute__((ext_vector_type(4)))  unsigned short u16x4;

// float -> bf16, round-to-nearest-even
static __device__ __forceinline__ unsigned short f2bf(float f) {
    unsigned int u = __float_as_uint(f);
    unsigned int r = (u + 0x7FFFu + ((u >> 16) & 1u)) >> 16;
    return (unsigned short)r;
}

// lgkm-drain + raw barrier (does NOT drain vmcnt: keeps global prefetches in flight)
static __device__ __forceinline__ void block_sync_lds() {
    asm volatile("s_waitcnt lgkmcnt(0)" ::: "memory");
    __builtin_amdgcn_s_barrier();
    asm volatile("" ::: "memory");
}

// 32^-0.5 * log2(e): q-scale with exp2 conversion folded in
#define SCALE2Q 0.25503487756f

// ---------------------------------------------------------------------------
// Kernel 1: pack weights to bf16. W[320][256]: rows 0..31 = scale2q*w_qk(q),
// rows 32..63 = w_qk(k), rows 64..319 = w_v.
// ---------------------------------------------------------------------------
__global__ void prep_w_kernel(const float* __restrict__ wqk,
                              const float* __restrict__ wv,
                              unsigned short* __restrict__ W) {
    int idx = blockIdx.x * 256 + threadIdx.x;
    int o = idx >> 8, c = idx & 255;
    float v;
    if (o < 64) { v = wqk[o * 256 + c]; if (o < 32) v *= SCALE2Q; }
    else        { v = wv[(o - 64) * 256 + c]; }
    W[idx] = f2bf(v);
}

// ---------------------------------------------------------------------------
// Kernel 2: xT[b][s][c] = bf16(x[b][c][s]).  64x64 tiles via LDS.
// ---------------------------------------------------------------------------
__global__ __launch_bounds__(256) void transpose_kernel(
        const float* __restrict__ x, unsigned short* __restrict__ xT) {
    __shared__ unsigned short tile[64][66];
    int b = blockIdx.x & 7;
    int rem = blockIdx.x >> 3;
    int ct = rem >> 6, st = rem & 63;
    int s0 = st * 64, c0 = ct * 64;
    int tid = threadIdx.x;
    int ss = tid & 63, cq = tid >> 6;
#pragma unroll
    for (int p = 0; p < 16; ++p) {
        int cc = p * 4 + cq;
        float v = x[(size_t)(b * 256 + c0 + cc) * 4096 + s0 + ss];
        tile[ss][cc] = f2bf(v);
    }
    __syncthreads();
#pragma unroll
    for (int p = 0; p < 8; ++p) {
        int idx = p * 256 + tid;
        int sr = idx >> 5, jj = idx & 31;
        unsigned int val = *(const unsigned int*)&tile[sr][jj * 2];
        *(unsigned int*)(xT + (size_t)(b * 4096 + s0 + sr) * 256 + c0 + jj * 2) = val;
    }
}

// ---------------------------------------------------------------------------
// Kernel 3: projection GEMM (MFMA 16x16x32, no LDS).
// ---------------------------------------------------------------------------
__global__ __launch_bounds__(256) void proj_kernel(
        const unsigned short* __restrict__ W,    // [320][256]
        const unsigned short* __restrict__ xT,   // [8][4096][256]
        unsigned short* __restrict__ qkT,        // [8][4096][64]
        unsigned short* __restrict__ vbuf) {     // [8][256][4096]
    const int b  = blockIdx.x & 7;
    const int sb = blockIdx.x >> 3;
    const int s0 = sb * 64;
    const int tid = threadIdx.x;
    const int w = tid >> 6, l = tid & 63;
    const int lg = l >> 4, ll = l & 15;
    const size_t xbase = (size_t)b * 4096 * 256;

    f32x4 acc[5][4];
#pragma unroll
    for (int ot = 0; ot < 5; ++ot)
#pragma unroll
        for (int st = 0; st < 4; ++st) acc[ot][st] = (f32x4)0.0f;

    for (int k0 = 0; k0 < 256; k0 += 32) {
        short8 bf[4], af[5];
#pragma unroll
        for (int st = 0; st < 4; ++st)
            bf[st] = *(const short8*)(xT + xbase + (size_t)(s0 + st * 16 + ll) * 256 + k0 + lg * 8);
#pragma unroll
        for (int ot = 0; ot < 5; ++ot)
            af[ot] = *(const short8*)(W + (size_t)(80 * w + ot * 16 + ll) * 256 + k0 + lg * 8);
#pragma unroll
        for (int ot = 0; ot < 5; ++ot)
#pragma unroll
            for (int st = 0; st < 4; ++st)
                acc[ot][st] = __builtin_amdgcn_mfma_f32_16x16x32_bf16(af[ot], bf[st], acc[ot][st], 0, 0, 0);
    }
#pragma unroll
    for (int ot = 0; ot < 5; ++ot) {
        int o0 = 80 * w + ot * 16 + lg * 4;
#pragma unroll
        for (int st = 0; st < 4; ++st) {
            int s = s0 + st * 16 + ll;
            if (o0 < 64) {
                u16x4 pk;
#pragma unroll
                for (int i = 0; i < 4; ++i) pk[i] = f2bf(acc[ot][st][i]);
                *(u16x4*)(qkT + (size_t)b * 4096 * 64 + (size_t)s * 64 + o0) = pk;
            } else {
#pragma unroll
                for (int i = 0; i < 4; ++i)
                    vbuf[(size_t)b * 256 * 4096 + (size_t)(o0 - 64 + i) * 4096 + s] = f2bf(acc[ot][st][i]);
            }
        }
    }
}

// ---------------------------------------------------------------------------
// Kernel 4: attention, producer/consumer wave split.
// grid 256 = 8 batches x 32 q-tiles of 128. 512 threads = 8 waves.
// Waves 0-3 (producers): swapped QK^T (mfma(K,Q), 32x32x16) for 32 q-rows,
//   exp2 (scale*log2e folded into q-weights), cvt_pk packing, 4x ds_write_b64
//   into row-rotate-swizzled P tile. Waves 4-7 (consumers): PV for 64 channels
//   x all 128 rows; P from LDS (b128, swizzled), V direct from L2 (dup=1).
// Double-buffered P, one lgkm-only barrier per 64-key tile. Single-buffered
// vf/kf reloaded after last use (loads span the barrier).
// ---------------------------------------------------------------------------
__global__ __launch_bounds__(512) void attn_kernel(
        const unsigned short* __restrict__ qkT,  // [8][4096][64] (q|k)
        const unsigned short* __restrict__ vbuf, // [8][256][4096]
        const float* __restrict__ x,             // [8][256][4096]
        const float* __restrict__ gamma,
        float* __restrict__ out) {
    __shared__ unsigned short p_lds[2][128][64];   // [q][key], byte ^ ((q&7)<<4)
    __shared__ float lsum_lds[128];

    const int b   = blockIdx.x & 7;
    const int sb  = blockIdx.x >> 3;
    const int s0  = sb * 128;
    const int tid = threadIdx.x;
    const int w   = tid >> 6;
    const int l   = tid & 63;
    const int l5  = l >> 5, l31 = l & 31;
    const int swz = (l31 & 7) << 4;
    const bool is_p = (w < 4);

    const size_t qk_base = (size_t)b * 4096 * 64;
    const size_t bx_base = (size_t)b * 256 * 4096;
    const unsigned short* kb  = qkT + qk_base;
    const unsigned short* vb0 = vbuf + bx_base;

    char* pbyte0 = (char*)&p_lds[0][0][0];
    char* pbyte1 = (char*)&p_lds[1][0][0];

    // producer state
    const int q0 = 32 * (w & 3);
    const int prow_off = (q0 + l31) * 128;
    short8 qf0, qf1;
    short8 kf[2][2];
    float psum = 0.f;

    // consumer state
    const int cb = 64 * (w & 3);
    const size_t voff0 = (size_t)(cb + l31) * 4096;
    const size_t voff1 = (size_t)(cb + 32 + l31) * 4096;
    f32x16 acc[4][2];
    short8 vf[2][4];

    if (is_p) {
        const unsigned short* qrow = qkT + qk_base + (size_t)(s0 + q0 + l31) * 64;
        qf0 = *(const short8*)(qrow + 8 * l5);
        qf1 = *(const short8*)(qrow + 16 + 8 * l5);
#pragma unroll
        for (int kt = 0; kt < 2; ++kt)
#pragma unroll
            for (int lh = 0; lh < 2; ++lh)
                kf[kt][lh] = *(const short8*)(kb + (size_t)(32 * kt + l31) * 64 + 32 + 16 * lh + 8 * l5);
    } else {
#pragma unroll
        for (int st = 0; st < 4; ++st)
#pragma unroll
            for (int ct = 0; ct < 2; ++ct) acc[st][ct] = (f32x16)0.0f;
#pragma unroll
        for (int ks = 0; ks < 4; ++ks) {
            vf[0][ks] = *(const short8*)(vb0 + voff0 + 16 * ks + 8 * l5);
            vf[1][ks] = *(const short8*)(vb0 + voff1 + 16 * ks + 8 * l5);
        }
    }

#define PRODUCE(T, PBYTE)                                                      \
    {                                                                          \
        f32x16 dd[2];                                                          \
        _Pragma("unroll") for (int kt = 0; kt < 2; ++kt) {                     \
            dd[kt] = (f32x16)0.0f;                                             \
            dd[kt] = __builtin_amdgcn_mfma_f32_32x32x16_bf16(kf[kt][0], qf0, dd[kt], 0, 0, 0); \
            dd[kt] = __builtin_amdgcn_mfma_f32_32x32x16_bf16(kf[kt][1], qf1, dd[kt], 0, 0, 0); \
        }                                                                      \
        if ((T) < 63) {                                                        \
            int tn_ = ((T) + 1) * 64;                                          \
            _Pragma("unroll") for (int kt = 0; kt < 2; ++kt)                   \
                _Pragma("unroll") for (int lh = 0; lh < 2; ++lh)               \
                    kf[kt][lh] = *(const short8*)(kb + (size_t)(tn_ + 32 * kt + l31) * 64 + 32 + 16 * lh + 8 * l5); \
        }                                                                      \
        _Pragma("unroll") for (int kt = 0; kt < 2; ++kt)                       \
            _Pragma("unroll") for (int g = 0; g < 4; ++g) {                    \
                float p0 = exp2f(dd[kt][4 * g + 0]);                           \
                float p1 = exp2f(dd[kt][4 * g + 1]);                           \
                float p2 = exp2f(dd[kt][4 * g + 2]);                           \
                float p3 = exp2f(dd[kt][4 * g + 3]);                           \
                psum += (p0 + p1) + (p2 + p3);                                 \
                unsigned int pw0, pw1;                                         \
                asm("v_cvt_pk_bf16_f32 %0, %1, %2" : "=v"(pw0) : "v"(p0), "v"(p1)); \
                asm("v_cvt_pk_bf16_f32 %0, %1, %2" : "=v"(pw1) : "v"(p2), "v"(p3)); \
                uint2 pv_; pv_.x = pw0; pv_.y = pw1;                           \
                *(uint2*)((PBYTE) + prow_off + ((64 * kt + 16 * g + 8 * l5) ^ swz)) = pv_; \
            }                                                                  \
    }

#define CONSUME(TM1, PBYTE, LOADV)                                             \
    {                                                                          \
        _Pragma("unroll") for (int ks = 0; ks < 4; ++ks) {                     \
            short8 pa[4];                                                      \
            _Pragma("unroll") for (int st = 0; st < 4; ++st)                   \
                pa[st] = *(const short8*)((PBYTE) + (32 * st + l31) * 128 + ((32 * ks + 16 * l5) ^ swz)); \
            _Pragma("unroll") for (int ct = 0; ct < 2; ++ct)                   \
                _Pragma("unroll") for (int st = 0; st < 4; ++st)               \
                    acc[st][ct] = __builtin_amdgcn_mfma_f32_32x32x16_bf16(pa[st], vf[ct][ks], acc[st][ct], 0, 0, 0); \
        }                                                                      \
        if (LOADV) {                                                           \
            int tv_ = ((TM1) + 1) * 64;                                        \
            _Pragma("unroll") for (int ks = 0; ks < 4; ++ks) {                 \
                vf[0][ks] = *(const short8*)(vb0 + voff0 + tv_ + 16 * ks + 8 * l5); \
                vf[1][ks] = *(const short8*)(vb0 + voff1 + tv_ + 16 * ks + 8 * l5); \
            }                                                                  \
        }                                                                      \
    }

#define STEP(T, PBW, PBR, DOC)                                                 \
    {                                                                          \
        if (is_p) PRODUCE(T, PBW)                                              \
        else if (DOC) CONSUME((T) - 1, PBR, 1)                                 \
        block_sync_lds();                                                      \
    }

    STEP(0, pbyte0, pbyte1, 0);
    for (int t = 1; t < 63; t += 2) {
        STEP(t,     pbyte1, pbyte0, 1);
        STEP(t + 1, pbyte0, pbyte1, 1);
    }
    STEP(63, pbyte1, pbyte0, 1);

    if (is_p) {
        float tot = psum + __shfl_xor(psum, 32);
        if (l5 == 0) lsum_lds[q0 + l31] = tot;
    } else {
        CONSUME(63, pbyte1, 0);
    }
    __syncthreads();

#undef STEP
#undef CONSUME
#undef PRODUCE

    // ---- epilogue (consumers): out = gamma*acc/lsum + x ----
    if (!is_p) {
        const float g = gamma[0];
#pragma unroll
        for (int st = 0; st < 4; ++st) {
#pragma unroll
            for (int rq = 0; rq < 4; ++rq) {
                int rbase = 32 * st + 8 * rq + 4 * l5;   // D row = (r&3)+8*(r>>2)+4*l5
                f32x4 ls = *(const f32x4*)&lsum_lds[rbase];
                f32x4 gi;
#pragma unroll
                for (int m = 0; m < 4; ++m) gi[m] = g / ls[m];
#pragma unroll
                for (int ct = 0; ct < 2; ++ct) {
                    int ch = cb + 32 * ct + l31;
                    size_t off = bx_base + (size_t)ch * 4096 + s0 + rbase;
                    f32x4 xv = *(const f32x4*)(x + off);
                    f32x4 o;
#pragma unroll
                    for (int m = 0; m < 4; ++m)
                        o[m] = gi[m] * acc[st][ct][4 * rq + m] + xv[m];
                    *(f32x4*)(out + off) = o;
                }
            }
        }
    }
}

// ---------------------------------------------------------------------------
extern "C" void kernel_launch(void* const* d_in, const int* in_sizes, int n_in,
                              void* d_out, int out_size, void* d_ws, size_t ws_size,
                              hipStream_t stream) {
    const float* x     = (const float*)d_in[0];
    const float* wqk   = (const float*)d_in[1];
    const float* wv    = (const float*)d_in[2];
    const float* gamma = (const float*)d_in[3];
    float* out = (float*)d_out;

    char* ws = (char*)d_ws;
    unsigned short* W    = (unsigned short*)(ws);                       // 160 KiB
    unsigned short* qkT  = (unsigned short*)(ws + 163840);              // 4 MiB
    unsigned short* xT   = (unsigned short*)(ws + 163840 + 4194304);    // 16 MiB
    unsigned short* vbuf = (unsigned short*)(ws + 163840 + 4194304 + 16777216); // 16 MiB

    hipLaunchKernelGGL(prep_w_kernel,    dim3(320),  dim3(256), 0, stream, wqk, wv, W);
    hipLaunchKernelGGL(transpose_kernel, dim3(2048), dim3(256), 0, stream, x, xT);
    hipLaunchKernelGGL(proj_kernel,      dim3(512),  dim3(256), 0, stream, W, xT, qkT, vbuf);
    hipLaunchKernelGGL(attn_kernel,      dim3(256),  dim3(512), 0, stream, qkT, vbuf, x, gamma, out);
}

// Round 5
// 164.492 us; speedup vs baseline: 1.2114x; 1.2114x over previous
//
#include <hip/hip_runtime.h>

typedef __attribute__((ext_vector_type(4)))  float f32x4;
typedef __attribute__((ext_vector_type(16))) float f32x16;
typedef __attribute__((ext_vector_type(8)))  short short8;
typedef __attribute__((ext_vector_type(4)))  unsigned short u16x4;

// float -> bf16, round-to-nearest-even
static __device__ __forceinline__ unsigned short f2bf(float f) {
    unsigned int u = __float_as_uint(f);
    unsigned int r = (u + 0x7FFFu + ((u >> 16) & 1u)) >> 16;
    return (unsigned short)r;
}

// lgkm-drain + raw barrier (does NOT drain vmcnt: keeps global prefetches in flight)
static __device__ __forceinline__ void block_sync_lds() {
    asm volatile("s_waitcnt lgkmcnt(0)" ::: "memory");
    __builtin_amdgcn_s_barrier();
    asm volatile("" ::: "memory");
}

// 32^-0.5 * log2(e): q-scale with exp2 conversion folded in
#define SCALE2Q 0.25503487756f

// ---------------------------------------------------------------------------
// Kernel 1: pack weights to bf16. W[320][256]: rows 0..31 = scale2q*w_qk(q),
// rows 32..63 = w_qk(k), rows 64..319 = w_v.
// ---------------------------------------------------------------------------
__global__ void prep_w_kernel(const float* __restrict__ wqk,
                              const float* __restrict__ wv,
                              unsigned short* __restrict__ W) {
    int idx = blockIdx.x * 256 + threadIdx.x;
    int o = idx >> 8, c = idx & 255;
    float v;
    if (o < 64) { v = wqk[o * 256 + c]; if (o < 32) v *= SCALE2Q; }
    else        { v = wv[(o - 64) * 256 + c]; }
    W[idx] = f2bf(v);
}

// ---------------------------------------------------------------------------
// Kernel 2: xT[b][s][c] = bf16(x[b][c][s]).  64x64 tiles via LDS.
// ---------------------------------------------------------------------------
__global__ __launch_bounds__(256) void transpose_kernel(
        const float* __restrict__ x, unsigned short* __restrict__ xT) {
    __shared__ unsigned short tile[64][66];
    int b = blockIdx.x & 7;
    int rem = blockIdx.x >> 3;
    int ct = rem >> 6, st = rem & 63;
    int s0 = st * 64, c0 = ct * 64;
    int tid = threadIdx.x;
    int ss = tid & 63, cq = tid >> 6;
#pragma unroll
    for (int p = 0; p < 16; ++p) {
        int cc = p * 4 + cq;
        float v = x[(size_t)(b * 256 + c0 + cc) * 4096 + s0 + ss];
        tile[ss][cc] = f2bf(v);
    }
    __syncthreads();
#pragma unroll
    for (int p = 0; p < 8; ++p) {
        int idx = p * 256 + tid;
        int sr = idx >> 5, jj = idx & 31;
        unsigned int val = *(const unsigned int*)&tile[sr][jj * 2];
        *(unsigned int*)(xT + (size_t)(b * 4096 + s0 + sr) * 256 + c0 + jj * 2) = val;
    }
}

// ---------------------------------------------------------------------------
// Kernel 3: projection GEMM (MFMA 16x16x32, no LDS).
// ---------------------------------------------------------------------------
__global__ __launch_bounds__(256) void proj_kernel(
        const unsigned short* __restrict__ W,    // [320][256]
        const unsigned short* __restrict__ xT,   // [8][4096][256]
        unsigned short* __restrict__ qkT,        // [8][4096][64]
        unsigned short* __restrict__ vbuf) {     // [8][256][4096]
    const int b  = blockIdx.x & 7;
    const int sb = blockIdx.x >> 3;
    const int s0 = sb * 64;
    const int tid = threadIdx.x;
    const int w = tid >> 6, l = tid & 63;
    const int lg = l >> 4, ll = l & 15;
    const size_t xbase = (size_t)b * 4096 * 256;

    f32x4 acc[5][4];
#pragma unroll
    for (int ot = 0; ot < 5; ++ot)
#pragma unroll
        for (int st = 0; st < 4; ++st) acc[ot][st] = (f32x4)0.0f;

    for (int k0 = 0; k0 < 256; k0 += 32) {
        short8 bf[4], af[5];
#pragma unroll
        for (int st = 0; st < 4; ++st)
            bf[st] = *(const short8*)(xT + xbase + (size_t)(s0 + st * 16 + ll) * 256 + k0 + lg * 8);
#pragma unroll
        for (int ot = 0; ot < 5; ++ot)
            af[ot] = *(const short8*)(W + (size_t)(80 * w + ot * 16 + ll) * 256 + k0 + lg * 8);
#pragma unroll
        for (int ot = 0; ot < 5; ++ot)
#pragma unroll
            for (int st = 0; st < 4; ++st)
                acc[ot][st] = __builtin_amdgcn_mfma_f32_16x16x32_bf16(af[ot], bf[st], acc[ot][st], 0, 0, 0);
    }
#pragma unroll
    for (int ot = 0; ot < 5; ++ot) {
        int o0 = 80 * w + ot * 16 + lg * 4;
#pragma unroll
        for (int st = 0; st < 4; ++st) {
            int s = s0 + st * 16 + ll;
            if (o0 < 64) {
                u16x4 pk;
#pragma unroll
                for (int i = 0; i < 4; ++i) pk[i] = f2bf(acc[ot][st][i]);
                *(u16x4*)(qkT + (size_t)b * 4096 * 64 + (size_t)s * 64 + o0) = pk;
            } else {
#pragma unroll
                for (int i = 0; i < 4; ++i)
                    vbuf[(size_t)b * 256 * 4096 + (size_t)(o0 - 64 + i) * 4096 + s] = f2bf(acc[ot][st][i]);
            }
        }
    }
}

// ---------------------------------------------------------------------------
// Kernel 4: attention, producer/consumer wave split with DISJOINT loops.
// grid 256 = 8 batches x 32 q-tiles of 128. 1024 threads = 16 waves.
// Waves 0-7 (producers): swapped QK^T mfma_16x16x32(K,Q) for 16 q-rows each
//   (lane = one q), exp2, cvt_pk, 4x ds_write_b64 into [chunk][q][8] P tile.
// Waves 8-15 (consumers): PV for 32 channels x all 128 q; 16x ds_read_b128
//   (throughput-floor layout), V single-buffered from L2 w/ 1-iter prefetch.
// Double-buffered P, ONE lgkm-only barrier per 64-key tile, skew = 1 tile.
// Roles live in separate loops so register pressure doesn't union (R4 bug).
// ---------------------------------------------------------------------------
__global__ __launch_bounds__(1024, 4) void attn_kernel(
        const unsigned short* __restrict__ qkT,  // [8][4096][64] (q|k)
        const unsigned short* __restrict__ vbuf, // [8][256][4096]
        const float* __restrict__ x,             // [8][256][4096]
        const float* __restrict__ gamma,
        float* __restrict__ out) {
    __shared__ unsigned short p_lds[2][8][128][8];   // 32 KiB, [buf][kchunk][q][8key]
    __shared__ float lsum_lds[128];

    const int b   = blockIdx.x & 7;
    const int sb  = blockIdx.x >> 3;
    const int s0  = sb * 128;
    const int tid = threadIdx.x;
    const int w   = tid >> 6;                   // 0..15
    const int l   = tid & 63;
    const int lg  = l >> 4, ll = l & 15;
    const int l5  = l >> 5, l31 = l & 31;

    const size_t qk_base = (size_t)b * 4096 * 64;
    const size_t bx_base = (size_t)b * 256 * 4096;

    if (w < 8) {
        // ================= PRODUCER: q-rows [s0+16w, s0+16w+16) =============
        const unsigned short* kb = qkT + qk_base + 32;   // k-half of qkT rows
        const short8 qf = *(const short8*)(qkT + qk_base + (size_t)(s0 + 16 * w + ll) * 64 + lg * 8);
        const int qrow = 16 * w + ll;                    // block-local q (lane's column)
        const int kch  = lg >> 1;                        // sub-chunk from lg
        const int koff = (lg & 1) * 8;                   // byte offset in 16B row
        short8 kf[4];
#pragma unroll
        for (int tt = 0; tt < 4; ++tt)
            kf[tt] = *(const short8*)(kb + (size_t)(tt * 16 + ll) * 64 + lg * 8);
        float psum = 0.f;
        const f32x4 zero4 = (f32x4)0.0f;

        for (int t = 0; t < 64; ++t) {
            f32x4 dd[4];
#pragma unroll
            for (int tt = 0; tt < 4; ++tt)
                dd[tt] = __builtin_amdgcn_mfma_f32_16x16x32_bf16(kf[tt], qf, zero4, 0, 0, 0);
            const int tn = (t < 63) ? (t + 1) * 64 : 0;
#pragma unroll
            for (int tt = 0; tt < 4; ++tt)
                kf[tt] = *(const short8*)(kb + (size_t)(tn + tt * 16 + ll) * 64 + lg * 8);
#pragma unroll
            for (int tt = 0; tt < 4; ++tt) {
                float p0 = exp2f(dd[tt][0]);
                float p1 = exp2f(dd[tt][1]);
                float p2 = exp2f(dd[tt][2]);
                float p3 = exp2f(dd[tt][3]);
                psum += (p0 + p1) + (p2 + p3);
                unsigned int pw0, pw1;
                asm("v_cvt_pk_bf16_f32 %0, %1, %2" : "=v"(pw0) : "v"(p0), "v"(p1));
                asm("v_cvt_pk_bf16_f32 %0, %1, %2" : "=v"(pw1) : "v"(p2), "v"(p3));
                uint2 pv_; pv_.x = pw0; pv_.y = pw1;
                *(uint2*)((char*)&p_lds[t & 1][2 * tt + kch][qrow][0] + koff) = pv_;
            }
            block_sync_lds();
        }
        // lane holds full-row partial for q = qrow over its 16 keys/iter;
        // reduce over lg (lanes ll, ll+16, ll+32, ll+48)
        psum += __shfl_xor(psum, 16);
        psum += __shfl_xor(psum, 32);
        if (lg == 0) lsum_lds[qrow] = psum;
    } else {
        // ================= CONSUMER: channels [32(w-8), +32) x 128 q ========
        const int ch = 32 * (w - 8) + l31;
        const unsigned short* vrow = vbuf + bx_base + (size_t)ch * 4096;
        f32x16 acc[4];
#pragma unroll
        for (int st = 0; st < 4; ++st) acc[st] = (f32x16)0.0f;
        short8 vf[4];
#pragma unroll
        for (int ks = 0; ks < 4; ++ks)
            vf[ks] = *(const short8*)(vrow + 16 * ks + 8 * l5);

        for (int t = 0; t < 64; ++t) {
            block_sync_lds();
#pragma unroll
            for (int ks = 0; ks < 4; ++ks) {
                short8 pa[4];
#pragma unroll
                for (int st = 0; st < 4; ++st)
                    pa[st] = *(const short8*)&p_lds[t & 1][2 * ks + l5][32 * st + l31][0];
#pragma unroll
                for (int st = 0; st < 4; ++st)
                    acc[st] = __builtin_amdgcn_mfma_f32_32x32x16_bf16(pa[st], vf[ks], acc[st], 0, 0, 0);
            }
            const int tv = (t < 63) ? (t + 1) * 64 : 0;
#pragma unroll
            for (int ks = 0; ks < 4; ++ks)
                vf[ks] = *(const short8*)(vrow + tv + 16 * ks + 8 * l5);
        }

        __syncthreads();   // wait for lsum_lds (producers' final write)

        // ---- epilogue: out = gamma*acc/lsum + x ----
        const float g = gamma[0];
#pragma unroll
        for (int st = 0; st < 4; ++st) {
#pragma unroll
            for (int rq = 0; rq < 4; ++rq) {
                int rbase = 32 * st + 8 * rq + 4 * l5;   // D row = (r&3)+8*(r>>2)+4*l5
                f32x4 ls = *(const f32x4*)&lsum_lds[rbase];
                f32x4 gi;
#pragma unroll
                for (int m = 0; m < 4; ++m) gi[m] = g / ls[m];
                size_t off = bx_base + (size_t)ch * 4096 + s0 + rbase;
                f32x4 xv = *(const f32x4*)(x + off);
                f32x4 o;
#pragma unroll
                for (int m = 0; m < 4; ++m)
                    o[m] = gi[m] * acc[st][4 * rq + m] + xv[m];
                *(f32x4*)(out + off) = o;
            }
        }
        return;
    }
    __syncthreads();       // producers match the consumers' epilogue barrier
}

// ---------------------------------------------------------------------------
extern "C" void kernel_launch(void* const* d_in, const int* in_sizes, int n_in,
                              void* d_out, int out_size, void* d_ws, size_t ws_size,
                              hipStream_t stream) {
    const float* x     = (const float*)d_in[0];
    const float* wqk   = (const float*)d_in[1];
    const float* wv    = (const float*)d_in[2];
    const float* gamma = (const float*)d_in[3];
    float* out = (float*)d_out;

    char* ws = (char*)d_ws;
    unsigned short* W    = (unsigned short*)(ws);                       // 160 KiB
    unsigned short* qkT  = (unsigned short*)(ws + 163840);              // 4 MiB
    unsigned short* xT   = (unsigned short*)(ws + 163840 + 4194304);    // 16 MiB
    unsigned short* vbuf = (unsigned short*)(ws + 163840 + 4194304 + 16777216); // 16 MiB

    hipLaunchKernelGGL(prep_w_kernel,    dim3(320),  dim3(256), 0, stream, wqk, wv, W);
    hipLaunchKernelGGL(transpose_kernel, dim3(2048), dim3(256), 0, stream, x, xT);
    hipLaunchKernelGGL(proj_kernel,      dim3(512),  dim3(256), 0, stream, W, xT, qkT, vbuf);
    hipLaunchKernelGGL(attn_kernel,      dim3(256),  dim3(1024), 0, stream, qkT, vbuf, x, gamma, out);
}

// Round 6
// 163.423 us; speedup vs baseline: 1.2193x; 1.0065x over previous
//
#include <hip/hip_runtime.h>

typedef __attribute__((ext_vector_type(4)))  float f32x4;
typedef __attribute__((ext_vector_type(16))) float f32x16;
typedef __attribute__((ext_vector_type(8)))  short short8;
typedef __attribute__((ext_vector_type(4)))  unsigned short u16x4;

// float -> bf16, round-to-nearest-even
static __device__ __forceinline__ unsigned short f2bf(float f) {
    unsigned int u = __float_as_uint(f);
    unsigned int r = (u + 0x7FFFu + ((u >> 16) & 1u)) >> 16;
    return (unsigned short)r;
}

// lgkm-drain + raw barrier (does NOT drain vmcnt: keeps global prefetches in flight)
static __device__ __forceinline__ void block_sync_lds() {
    asm volatile("s_waitcnt lgkmcnt(0)" ::: "memory");
    __builtin_amdgcn_s_barrier();
    asm volatile("" ::: "memory");
}

// 32^-0.5 * log2(e): q-scale with exp2 conversion folded in
#define SCALE2Q 0.25503487756f

// ---------------------------------------------------------------------------
// Kernel 1: pack weights to bf16. W[320][256]: rows 0..31 = scale2q*w_qk(q),
// rows 32..63 = w_qk(k), rows 64..319 = w_v.
// ---------------------------------------------------------------------------
__global__ void prep_w_kernel(const float* __restrict__ wqk,
                              const float* __restrict__ wv,
                              unsigned short* __restrict__ W) {
    int idx = blockIdx.x * 256 + threadIdx.x;
    int o = idx >> 8, c = idx & 255;
    float v;
    if (o < 64) { v = wqk[o * 256 + c]; if (o < 32) v *= SCALE2Q; }
    else        { v = wv[(o - 64) * 256 + c]; }
    W[idx] = f2bf(v);
}

// ---------------------------------------------------------------------------
// Kernel 2: xT[b][s][c] = bf16(x[b][c][s]).  64x64 tiles via LDS.
// ---------------------------------------------------------------------------
__global__ __launch_bounds__(256) void transpose_kernel(
        const float* __restrict__ x, unsigned short* __restrict__ xT) {
    __shared__ unsigned short tile[64][66];
    int b = blockIdx.x & 7;
    int rem = blockIdx.x >> 3;
    int ct = rem >> 6, st = rem & 63;
    int s0 = st * 64, c0 = ct * 64;
    int tid = threadIdx.x;
    int ss = tid & 63, cq = tid >> 6;
#pragma unroll
    for (int p = 0; p < 16; ++p) {
        int cc = p * 4 + cq;
        float v = x[(size_t)(b * 256 + c0 + cc) * 4096 + s0 + ss];
        tile[ss][cc] = f2bf(v);
    }
    __syncthreads();
#pragma unroll
    for (int p = 0; p < 8; ++p) {
        int idx = p * 256 + tid;
        int sr = idx >> 5, jj = idx & 31;
        unsigned int val = *(const unsigned int*)&tile[sr][jj * 2];
        *(unsigned int*)(xT + (size_t)(b * 4096 + s0 + sr) * 256 + c0 + jj * 2) = val;
    }
}

// ---------------------------------------------------------------------------
// Kernel 3: projection GEMM (MFMA 16x16x32, no LDS).
// ---------------------------------------------------------------------------
__global__ __launch_bounds__(256) void proj_kernel(
        const unsigned short* __restrict__ W,    // [320][256]
        const unsigned short* __restrict__ xT,   // [8][4096][256]
        unsigned short* __restrict__ qkT,        // [8][4096][64]
        unsigned short* __restrict__ vbuf) {     // [8][256][4096]
    const int b  = blockIdx.x & 7;
    const int sb = blockIdx.x >> 3;
    const int s0 = sb * 64;
    const int tid = threadIdx.x;
    const int w = tid >> 6, l = tid & 63;
    const int lg = l >> 4, ll = l & 15;
    const size_t xbase = (size_t)b * 4096 * 256;

    f32x4 acc[5][4];
#pragma unroll
    for (int ot = 0; ot < 5; ++ot)
#pragma unroll
        for (int st = 0; st < 4; ++st) acc[ot][st] = (f32x4)0.0f;

    for (int k0 = 0; k0 < 256; k0 += 32) {
        short8 bf[4], af[5];
#pragma unroll
        for (int st = 0; st < 4; ++st)
            bf[st] = *(const short8*)(xT + xbase + (size_t)(s0 + st * 16 + ll) * 256 + k0 + lg * 8);
#pragma unroll
        for (int ot = 0; ot < 5; ++ot)
            af[ot] = *(const short8*)(W + (size_t)(80 * w + ot * 16 + ll) * 256 + k0 + lg * 8);
#pragma unroll
        for (int ot = 0; ot < 5; ++ot)
#pragma unroll
            for (int st = 0; st < 4; ++st)
                acc[ot][st] = __builtin_amdgcn_mfma_f32_16x16x32_bf16(af[ot], bf[st], acc[ot][st], 0, 0, 0);
    }
#pragma unroll
    for (int ot = 0; ot < 5; ++ot) {
        int o0 = 80 * w + ot * 16 + lg * 4;
#pragma unroll
        for (int st = 0; st < 4; ++st) {
            int s = s0 + st * 16 + ll;
            if (o0 < 64) {
                u16x4 pk;
#pragma unroll
                for (int i = 0; i < 4; ++i) pk[i] = f2bf(acc[ot][st][i]);
                *(u16x4*)(qkT + (size_t)b * 4096 * 64 + (size_t)s * 64 + o0) = pk;
            } else {
#pragma unroll
                for (int i = 0; i < 4; ++i)
                    vbuf[(size_t)b * 256 * 4096 + (size_t)(o0 - 64 + i) * 4096 + s] = f2bf(acc[ot][st][i]);
            }
        }
    }
}

// ---------------------------------------------------------------------------
// Kernel 4: attention, producer/consumer split + channel-split blocks.
// grid 512 = 8 batches x 32 q-tiles x 2 channel-halves; 512 thr = 8 waves.
// => 2 independent blocks/CU (32 waves/CU): barrier convoys decouple.
// Waves 0-3 (producers): swapped QK^T mfma_32x32x16(K,Q), 32 q-rows/wave,
//   exp2, cvt_pk, 8x ds_write_b64 into [kchunk][q][8] P tile (computed
//   redundantly in both channel-half blocks; QK is 11% of FLOPs).
// Waves 4-7 (consumers): PV for 32 channels x 128 q each (128-ch half),
//   16x ds_read_b128 + 16x MFMA 32x32x16 per tile, setprio(1) around MFMAs.
// Double-buffered P, one lgkm-only barrier per 64-key tile.
// ---------------------------------------------------------------------------
__global__ __launch_bounds__(512, 4) void attn_kernel(
        const unsigned short* __restrict__ qkT,  // [8][4096][64] (q|k)
        const unsigned short* __restrict__ vbuf, // [8][256][4096]
        const float* __restrict__ x,             // [8][256][4096]
        const float* __restrict__ gamma,
        float* __restrict__ out) {
    __shared__ unsigned short p_lds[2][8][128][8];   // 32 KiB, [buf][kchunk][q][8key]
    __shared__ float lsum_lds[128];

    const int b     = blockIdx.x & 7;        // batch == XCD (L2 pinning)
    const int sb    = (blockIdx.x >> 3) & 31;
    const int chalf = blockIdx.x >> 8;       // 0/1: channel half
    const int s0    = sb * 128;
    const int tid = threadIdx.x;
    const int w   = tid >> 6;                // 0..7
    const int l   = tid & 63;
    const int l5  = l >> 5, l31 = l & 31;

    const size_t qk_base = (size_t)b * 4096 * 64;
    const size_t bx_base = (size_t)b * 256 * 4096;

    if (w < 4) {
        // ============ PRODUCER: q-rows [s0+32w, s0+32w+32), all 64 keys =====
        const unsigned short* kb = qkT + qk_base + 32;     // k-half of rows
        const int q = 32 * w + l31;                        // block-local q
        const unsigned short* qrow = qkT + qk_base + (size_t)(s0 + q) * 64;
        short8 qf[2];
        qf[0] = *(const short8*)(qrow + 8 * l5);           // latent 0..15
        qf[1] = *(const short8*)(qrow + 16 + 8 * l5);      // latent 16..31
        short8 kf[2][2];
#pragma unroll
        for (int kt = 0; kt < 2; ++kt)
#pragma unroll
            for (int h = 0; h < 2; ++h)
                kf[kt][h] = *(const short8*)(kb + (size_t)(32 * kt + l31) * 64 + 16 * h + 8 * l5);
        float psum = 0.f;
        const f32x16 zero16 = (f32x16)0.0f;

        for (int t = 0; t < 64; ++t) {
            f32x16 dd[2];
#pragma unroll
            for (int kt = 0; kt < 2; ++kt) {
                dd[kt] = __builtin_amdgcn_mfma_f32_32x32x16_bf16(kf[kt][0], qf[0], zero16, 0, 0, 0);
                dd[kt] = __builtin_amdgcn_mfma_f32_32x32x16_bf16(kf[kt][1], qf[1], dd[kt], 0, 0, 0);
            }
            const int tn = (t < 63) ? (t + 1) * 64 : 0;
#pragma unroll
            for (int kt = 0; kt < 2; ++kt)
#pragma unroll
                for (int h = 0; h < 2; ++h)
                    kf[kt][h] = *(const short8*)(kb + (size_t)(tn + 32 * kt + l31) * 64 + 16 * h + 8 * l5);
            // D[key][q]: col=l31 (q), key = (r&3) + 8*(r>>2) + 4*l5 + 32*kt
#pragma unroll
            for (int kt = 0; kt < 2; ++kt)
#pragma unroll
                for (int rq = 0; rq < 4; ++rq) {
                    float p0 = exp2f(dd[kt][4 * rq + 0]);
                    float p1 = exp2f(dd[kt][4 * rq + 1]);
                    float p2 = exp2f(dd[kt][4 * rq + 2]);
                    float p3 = exp2f(dd[kt][4 * rq + 3]);
                    psum += (p0 + p1) + (p2 + p3);
                    unsigned int pw0, pw1;
                    asm("v_cvt_pk_bf16_f32 %0, %1, %2" : "=v"(pw0) : "v"(p0), "v"(p1));
                    asm("v_cvt_pk_bf16_f32 %0, %1, %2" : "=v"(pw1) : "v"(p2), "v"(p3));
                    uint2 pv_; pv_.x = pw0; pv_.y = pw1;
                    // kchunk = rq + 4*kt ; key&7 = (r&3) + 4*l5
                    *(uint2*)((char*)&p_lds[t & 1][rq + 4 * kt][q][0] + 8 * l5) = pv_;
                }
            block_sync_lds();
        }
        // lane's psum covers q's keys at offsets {4*l5 + ...}; partner is l^32
        psum += __shfl_xor(psum, 32);
        if (l5 == 0) lsum_lds[q] = psum;
        __syncthreads();                       // matches consumers' barrier 65
    } else {
        // ============ CONSUMER: channel 128*chalf + 32*(w-4) + l31 ==========
        const int ch = 128 * chalf + 32 * (w - 4) + l31;
        const unsigned short* vrow = vbuf + bx_base + (size_t)ch * 4096;
        f32x16 acc[4];
#pragma unroll
        for (int st = 0; st < 4; ++st) acc[st] = (f32x16)0.0f;
        short8 vf[4];
#pragma unroll
        for (int ks = 0; ks < 4; ++ks)
            vf[ks] = *(const short8*)(vrow + 16 * ks + 8 * l5);

        for (int t = 0; t < 64; ++t) {
            block_sync_lds();
            __builtin_amdgcn_s_setprio(1);
#pragma unroll
            for (int ks = 0; ks < 4; ++ks) {
                short8 pa[4];
#pragma unroll
                for (int st = 0; st < 4; ++st)
                    pa[st] = *(const short8*)&p_lds[t & 1][2 * ks + l5][32 * st + l31][0];
#pragma unroll
                for (int st = 0; st < 4; ++st)
                    acc[st] = __builtin_amdgcn_mfma_f32_32x32x16_bf16(pa[st], vf[ks], acc[st], 0, 0, 0);
            }
            __builtin_amdgcn_s_setprio(0);
            const int tv = (t < 63) ? (t + 1) * 64 : 0;
#pragma unroll
            for (int ks = 0; ks < 4; ++ks)
                vf[ks] = *(const short8*)(vrow + tv + 16 * ks + 8 * l5);
        }

        __syncthreads();   // wait for lsum_lds (producers' final write)

        // ---- epilogue: out = gamma*acc/lsum + x ----
        const float g = gamma[0];
#pragma unroll
        for (int st = 0; st < 4; ++st) {
#pragma unroll
            for (int rq = 0; rq < 4; ++rq) {
                int rbase = 32 * st + 8 * rq + 4 * l5;   // D row = (r&3)+8*(r>>2)+4*l5
                f32x4 ls = *(const f32x4*)&lsum_lds[rbase];
                f32x4 gi;
#pragma unroll
                for (int m = 0; m < 4; ++m) gi[m] = g / ls[m];
                size_t off = bx_base + (size_t)ch * 4096 + s0 + rbase;
                f32x4 xv = *(const f32x4*)(x + off);
                f32x4 o;
#pragma unroll
                for (int m = 0; m < 4; ++m)
                    o[m] = gi[m] * acc[st][4 * rq + m] + xv[m];
                *(f32x4*)(out + off) = o;
            }
        }
    }
}

// ---------------------------------------------------------------------------
extern "C" void kernel_launch(void* const* d_in, const int* in_sizes, int n_in,
                              void* d_out, int out_size, void* d_ws, size_t ws_size,
                              hipStream_t stream) {
    const float* x     = (const float*)d_in[0];
    const float* wqk   = (const float*)d_in[1];
    const float* wv    = (const float*)d_in[2];
    const float* gamma = (const float*)d_in[3];
    float* out = (float*)d_out;

    char* ws = (char*)d_ws;
    unsigned short* W    = (unsigned short*)(ws);                       // 160 KiB
    unsigned short* qkT  = (unsigned short*)(ws + 163840);              // 4 MiB
    unsigned short* xT   = (unsigned short*)(ws + 163840 + 4194304);    // 16 MiB
    unsigned short* vbuf = (unsigned short*)(ws + 163840 + 4194304 + 16777216); // 16 MiB

    hipLaunchKernelGGL(prep_w_kernel,    dim3(320),  dim3(256), 0, stream, wqk, wv, W);
    hipLaunchKernelGGL(transpose_kernel, dim3(2048), dim3(256), 0, stream, x, xT);
    hipLaunchKernelGGL(proj_kernel,      dim3(512),  dim3(256), 0, stream, W, xT, qkT, vbuf);
    hipLaunchKernelGGL(attn_kernel,      dim3(512),  dim3(512), 0, stream, qkT, vbuf, x, gamma, out);
}